// Round 14
// baseline (302.652 us; speedup 1.0000x reference)
//
#include <hip/hip_runtime.h>
#include <stdint.h>

// VectorQuantize on MI355X (gfx950) — bf16x3 MFMA distance-GEMM + argmin.
// Round 14: r13 skeleton (BM=256 x BN=256, 8 waves 64x128, X3/E2 counted
// vmcnt(4) ring, rt-major XCD mapping, pinned ds_read + counted lgkmcnt)
// with payload switched 16x16x32 -> 32x32x16 (µbench +10-15% MFMA rate,
// half the MFMA instructions). acc[2][4] f32x16; lane-owns-row epilogue.
// d_out: [0..N*DIM) quantized (fp32), [N*DIM..+N) ind (fp32), loss, perplexity.

#define N_VEC 16384
#define M_CODES 8192
#define DIM 256
#define BETA 0.25f

#define NSLICE 4
#define SLICE_CODES 2048
#define BM 256
#define BN 256
#define NPART 8                  // NSLICE * 2 col groups

#define XSLOT 32768              // xh 16K | xl 16K   (256 rows x 64B)
#define ESLOT 32768              // eh 16K | el 16K   (256 rows x 64B)
#define EBASE (3 * XSLOT)
#define LDS_TOTAL (3 * XSLOT + 2 * ESLOT)   // 163840 = 160 KiB exactly
#define NSTEPS 64                // 8 ct x 8 kc (K=32 per step)

typedef __attribute__((ext_vector_type(16))) float f32x16;
typedef __attribute__((ext_vector_type(4))) int i32x4;
typedef __attribute__((ext_vector_type(8))) __bf16 bf16x8;

__device__ __forceinline__ void gll16(const void* g, const void* lds_p) {
    __builtin_amdgcn_global_load_lds(
        (const __attribute__((address_space(1))) uint32_t*)(uintptr_t)g,
        (__attribute__((address_space(3))) uint32_t*)(uint32_t)(uintptr_t)lds_p,
        16, 0, 0);
}
#define SB0() __builtin_amdgcn_sched_barrier(0)
#define DSR(DST, ADDR, OFF) \
    asm volatile("ds_read_b128 %0, %1 offset:" #OFF : "=v"(DST) : "v"(ADDR))
#define LGKM(N) asm volatile("s_waitcnt lgkmcnt(" #N ")" ::: "memory")

__device__ __forceinline__ ushort f2bf(float f) {
    uint32_t u = __float_as_uint(f);
    return (ushort)((u + 0x7FFFu + ((u >> 16) & 1u)) >> 16);  // RNE
}
__device__ __forceinline__ float bf2f(ushort h) {
    return __uint_as_float(((uint32_t)h) << 16);
}

// ---- fused: split fp32 -> bf16 hi/lo for x and e, e2, zero counts/loss ----
__global__ __launch_bounds__(256) void prep_kernel(
    const float* __restrict__ x, const float* __restrict__ emb,
    ushort* __restrict__ xh, ushort* __restrict__ xl,
    ushort* __restrict__ eh, ushort* __restrict__ el,
    float* __restrict__ e2, unsigned* __restrict__ counts,
    float* __restrict__ loss_acc) {
    if (blockIdx.x < 8) {
        int4 z = {0, 0, 0, 0};
        ((int4*)counts)[blockIdx.x * 256 + threadIdx.x] = z;
        if (blockIdx.x == 0 && threadIdx.x == 0) *loss_acc = 0.0f;
    }
    const int wave = threadIdx.x >> 6;
    const int lane = threadIdx.x & 63;
    const int row = blockIdx.x * 4 + wave;

    const float* src;
    ushort* ph;
    ushort* pl;
    bool is_e;
    int er = row - N_VEC;
    if (row < N_VEC) {
        src = x + (size_t)row * DIM;
        ph = xh + (size_t)row * DIM;
        pl = xl + (size_t)row * DIM;
        is_e = false;
    } else {
        src = emb + (size_t)er * DIM;
        ph = eh + (size_t)er * DIM;
        pl = el + (size_t)er * DIM;
        is_e = true;
    }
    float4 v = *(const float4*)(src + lane * 4);
    ushort h0 = f2bf(v.x), h1 = f2bf(v.y), h2 = f2bf(v.z), h3 = f2bf(v.w);
    ushort l0 = f2bf(v.x - bf2f(h0)), l1 = f2bf(v.y - bf2f(h1));
    ushort l2 = f2bf(v.z - bf2f(h2)), l3 = f2bf(v.w - bf2f(h3));
    *(ushort4*)(ph + lane * 4) = make_ushort4(h0, h1, h2, h3);
    *(ushort4*)(pl + lane * 4) = make_ushort4(l0, l1, l2, l3);
    if (is_e) {
        float s = v.x * v.x + v.y * v.y + v.z * v.z + v.w * v.w;
        #pragma unroll
        for (int off = 32; off; off >>= 1) s += __shfl_xor(s, off);
        if (lane == 0) e2[er] = s;
    }
}

// ------ main: bf16x3 32x32x16 MFMA distance GEMM, X3/E2 ring, argmin ----
__global__ __launch_bounds__(512, 1) void vq_mfma_kernel(
    const ushort* __restrict__ xh, const ushort* __restrict__ xl,
    const ushort* __restrict__ eh, const ushort* __restrict__ el,
    const float* __restrict__ e2g, unsigned long long* __restrict__ partials) {
    extern __shared__ char lds[];

    const int t = threadIdx.x;
    const int lane = t & 63;
    const int wv = t >> 6;          // 0..7
    const int l31 = lane & 31;
    const int lh5 = lane >> 5;      // 0/1

    // rt-major mapping: XCD = bid%8 = rt%8 -> slice-siblings co-XCD
    const int rt = blockIdx.x & 63;
    const int slice = blockIdx.x >> 6;   // 0..3
    const int row0 = rt * BM;
    const int cslice0 = slice * SLICE_CODES;

    const int wr0 = (wv & 3) * 64;   // wave row group 0..192 (fi in {0,1} x 32)
    const int wch = wv >> 2;         // wave col group (128 codes; fj in 0..3 x 32)

    // ---- fragment LDS byte bases for 32x32x16 (k-half chunked, swizzled)
    // A frag (fi, kh): row = wr0 + fi*32 + l31, chunk c = 2*kh + lh5,
    // stored slot = c ^ ((row>>1)&3); fi adds +2048 (swizzle invariant, row+32)
    const int rowA = wr0 + l31;
    const int swzA = (rowA >> 1) & 3;
    const int byteA_k0 = rowA * 64 + (((0 + lh5) ^ swzA) << 4);
    const int byteA_k1 = rowA * 64 + (((2 + lh5) ^ swzA) << 4);
    const int rowB = wch * 128 + l31;
    const int swzB = (rowB >> 1) & 3;
    const int byteB_k0 = rowB * 64 + (((0 + lh5) ^ swzB) << 4);
    const int byteB_k1 = rowB * 64 + (((2 + lh5) ^ swzB) << 4);

    // ---- staging: linear LDS dest, inverse-swizzled global source (as r13)
    const int s0 = wv * 128 + lane;
    const int s1 = s0 + 64;
    const int r0s = s0 >> 2, r1s = s1 >> 2;
    const int c0s = ((s0 & 3) ^ ((s0 >> 3) & 3)) << 3;
    const int c1s = ((s1 & 3) ^ ((s1 >> 3) & 3)) << 3;

    const ushort* pxh_a = xh + (size_t)(row0 + r0s) * DIM + c0s;
    const ushort* pxh_b = xh + (size_t)(row0 + r1s) * DIM + c1s;
    const ushort* pxl_a = xl + (size_t)(row0 + r0s) * DIM + c0s;
    const ushort* pxl_b = xl + (size_t)(row0 + r1s) * DIM + c1s;
    const ushort* peh_a = eh + (size_t)(cslice0 + r0s) * DIM + c0s;
    const ushort* peh_b = eh + (size_t)(cslice0 + r1s) * DIM + c1s;
    const ushort* pel_a = el + (size_t)(cslice0 + r0s) * DIM + c0s;
    const ushort* pel_b = el + (size_t)(cslice0 + r1s) * DIM + c1s;
    const int wdst = wv * 2048;

    auto stage_X = [&](int slot, int s) {   // 4 gll
        char* b = lds + slot * XSLOT + wdst;
        const int xo = (s & 7) * 32;
        gll16(pxh_a + xo, b);
        gll16(pxh_b + xo, b + 1024);
        gll16(pxl_a + xo, b + 16384);
        gll16(pxl_b + xo, b + 16384 + 1024);
    };
    auto stage_E = [&](int slot, int s) {   // 4 gll
        char* b = lds + EBASE + slot * ESLOT + wdst;
        const size_t eo = ((size_t)(s >> 3) << 16) + (s & 7) * 32;  // ct*BN*DIM + kc*32
        gll16(peh_a + eo, b);
        gll16(peh_b + eo, b + 1024);
        gll16(pel_a + eo, b + 16384);
        gll16(pel_b + eo, b + 16384 + 1024);
    };

    unsigned long long bestp = ~0ull;   // lane-owned running (ord<<32 | col)

    f32x16 acc[2][4];
    const f32x16 ZF = {};
    #pragma unroll
    for (int fi = 0; fi < 2; ++fi)
        #pragma unroll
        for (int fj = 0; fj < 4; ++fj) acc[fi][fj] = ZF;

    float e2r[4];

#define MFMA32(A, B, C) __builtin_amdgcn_mfma_f32_32x32x16_bf16(A, B, C, 0, 0, 0)
#define HHLH(FJ, B0R, B1R) do {                                  \
    bf16x8 bh0_ = __builtin_bit_cast(bf16x8, B0R);               \
    bf16x8 bh1_ = __builtin_bit_cast(bf16x8, B1R);               \
    acc[0][FJ] = MFMA32(A00, bh0_, acc[0][FJ]);                  \
    acc[1][FJ] = MFMA32(A10, bh0_, acc[1][FJ]);                  \
    acc[0][FJ] = MFMA32(A01, bh1_, acc[0][FJ]);                  \
    acc[1][FJ] = MFMA32(A11, bh1_, acc[1][FJ]);                  \
    acc[0][FJ] = MFMA32(L00, bh0_, acc[0][FJ]);                  \
    acc[1][FJ] = MFMA32(L10, bh0_, acc[1][FJ]);                  \
    acc[0][FJ] = MFMA32(L01, bh1_, acc[0][FJ]);                  \
    acc[1][FJ] = MFMA32(L11, bh1_, acc[1][FJ]);                  \
    } while (0)
#define HLB(FJ, B0R, B1R) do {                                   \
    bf16x8 bl0_ = __builtin_bit_cast(bf16x8, B0R);               \
    bf16x8 bl1_ = __builtin_bit_cast(bf16x8, B1R);               \
    acc[0][FJ] = MFMA32(A00, bl0_, acc[0][FJ]);                  \
    acc[1][FJ] = MFMA32(A10, bl0_, acc[1][FJ]);                  \
    acc[0][FJ] = MFMA32(A01, bl1_, acc[0][FJ]);                  \
    acc[1][FJ] = MFMA32(A11, bl1_, acc[1][FJ]);                  \
    } while (0)

    // prologue FIFO: X(0), E(0), X(1)
    stage_X(0, 0); SB0();
    stage_E(0, 0); SB0();
    stage_X(1, 1); SB0();

    int xsl = 0;  // X slot of current step = s%3
    for (int s = 0; s < NSTEPS; ++s) {
        // entry: drain X(s)+E(s); keep X(s+1) (4) in flight
        if (s == NSTEPS - 1) {
            asm volatile("s_waitcnt vmcnt(0)" ::: "memory");
        } else {
            asm volatile("s_waitcnt vmcnt(4)" ::: "memory");
        }
        __builtin_amdgcn_s_barrier();
        SB0();
        if ((s & 7) == 0) {
            const int cb = cslice0 + (s >> 3) * BN + wch * 128 + l31;
            #pragma unroll
            for (int fj = 0; fj < 4; ++fj) e2r[fj] = e2g[cb + fj * 32];
            SB0();
        }
        if (s + 1 < NSTEPS) { stage_E((s + 1) & 1, s + 1); SB0(); }
        if (s + 2 < NSTEPS) { stage_X((xsl >= 1) ? xsl - 1 : 2, s + 2); SB0(); }

        const uint32_t ax = (uint32_t)(uintptr_t)(lds + xsl * XSLOT);
        const uint32_t bx = (uint32_t)(uintptr_t)(lds + EBASE + (s & 1) * ESLOT);
        const uint32_t vAk0 = ax + (uint32_t)byteA_k0;
        const uint32_t vAk1 = ax + (uint32_t)byteA_k1;
        const uint32_t vBk0 = bx + (uint32_t)byteB_k0;
        const uint32_t vBk1 = bx + (uint32_t)byteB_k1;

        // pinned top batch: 8 A-frags + first B-pair (10 reads)
        i32x4 a00, a01, a10, a11, q00, q01, q10, q11, b0, b1, p0, p1;
        DSR(a00, vAk0, 0);     DSR(a01, vAk1, 0);
        DSR(a10, vAk0, 2048);  DSR(a11, vAk1, 2048);
        DSR(q00, vAk0, 16384); DSR(q01, vAk1, 16384);
        DSR(q10, vAk0, 18432); DSR(q11, vAk1, 18432);
        DSR(b0, vBk0, 0);      DSR(b1, vBk1, 0);
        __builtin_amdgcn_s_setprio(1);
        DSR(p0, vBk0, 2048);   DSR(p1, vBk1, 2048);
        LGKM(2); SB0();

        bf16x8 A00 = __builtin_bit_cast(bf16x8, a00);
        bf16x8 A01 = __builtin_bit_cast(bf16x8, a01);
        bf16x8 A10 = __builtin_bit_cast(bf16x8, a10);
        bf16x8 A11 = __builtin_bit_cast(bf16x8, a11);
        bf16x8 L00 = __builtin_bit_cast(bf16x8, q00);
        bf16x8 L01 = __builtin_bit_cast(bf16x8, q01);
        bf16x8 L10 = __builtin_bit_cast(bf16x8, q10);
        bf16x8 L11 = __builtin_bit_cast(bf16x8, q11);

        HHLH(0, b0, b1);
        DSR(b0, vBk0, 4096);  DSR(b1, vBk1, 4096);
        LGKM(2); SB0();
        HHLH(1, p0, p1);
        DSR(p0, vBk0, 6144);  DSR(p1, vBk1, 6144);
        LGKM(2); SB0();
        HHLH(2, b0, b1);
        LGKM(0); SB0();
        HHLH(3, p0, p1);

        // hl region: blo at +16384
        DSR(b0, vBk0, 16384); DSR(b1, vBk1, 16384);
        DSR(p0, vBk0, 18432); DSR(p1, vBk1, 18432);
        LGKM(2); SB0();
        HLB(0, b0, b1);
        DSR(b0, vBk0, 20480); DSR(b1, vBk1, 20480);
        LGKM(2); SB0();
        HLB(1, p0, p1);
        DSR(p0, vBk0, 22528); DSR(p1, vBk1, 22528);
        LGKM(2); SB0();
        HLB(2, b0, b1);
        LGKM(0); SB0();
        HLB(3, p0, p1);
        __builtin_amdgcn_s_setprio(0);
        xsl = (xsl == 2) ? 0 : xsl + 1;

        if ((s & 7) == 7) {
            // epilogue for ct = s>>3: score = e2[c] - 2*dot
            // C/D: col = lane&31, row = (reg&3) + 8*(reg>>2) + 4*(lane>>5)
            const int cb = cslice0 + (s >> 3) * BN + wch * 128;
            #pragma unroll
            for (int fi = 0; fi < 2; ++fi)
                #pragma unroll
                for (int reg = 0; reg < 16; ++reg) {
                    float m = e2r[0] - 2.0f * acc[fi][0][reg];
                    int cf = 0;
                    float s1 = e2r[1] - 2.0f * acc[fi][1][reg];
                    if (s1 < m) { m = s1; cf = 1; }
                    float s2 = e2r[2] - 2.0f * acc[fi][2][reg];
                    if (s2 < m) { m = s2; cf = 2; }
                    float s3 = e2r[3] - 2.0f * acc[fi][3][reg];
                    if (s3 < m) { m = s3; cf = 3; }
                    float mr = m;
                    #pragma unroll
                    for (int off = 1; off < 32; off <<= 1)
                        mr = fminf(mr, __shfl_xor(mr, off));
                    unsigned long long bal = __ballot(m == mr);
                    unsigned mask32 = (unsigned)(bal >> (lane & 32));
                    int win = __ffs((int)mask32) - 1;
                    int cfw = __shfl(cf, win | (lane & 32));
                    int col = cb + cfw * 32 + win;
                    if (l31 == ((fi << 4) | ((reg >> 2) << 2) | (reg & 3))) {
                        uint32_t u = __float_as_uint(mr);
                        uint32_t ord = (u & 0x80000000u) ? ~u : (u | 0x80000000u);
                        unsigned long long pk =
                            ((unsigned long long)ord << 32) | (unsigned)col;
                        if (pk < bestp) bestp = pk;
                    }
                }
            #pragma unroll
            for (int fi = 0; fi < 2; ++fi)
                #pragma unroll
                for (int fj = 0; fj < 4; ++fj) acc[fi][fj] = ZF;
        }
    }
#undef HHLH
#undef HLB
#undef MFMA32

    // lane-owned row writeback (each lane owns exactly one of the wave's 64 rows)
    {
        const int fi_o = (lane >> 4) & 1;
        const int rhi = (lane >> 2) & 3;
        const int rlo = lane & 3;
        const int half = lane >> 5;
        const int row = row0 + wr0 + fi_o * 32 + rlo + 8 * rhi + 4 * half;
        partials[(size_t)(slice * 2 + wch) * N_VEC + row] = bestp;
    }
}

// ---------------- fused: per-row min over partials + gather + loss + counts
__global__ __launch_bounds__(256) void finish_kernel(
    const float* __restrict__ x, const float* __restrict__ emb,
    const unsigned long long* __restrict__ partials,
    float* __restrict__ out_ind, float* __restrict__ out_q,
    unsigned* __restrict__ counts, float* __restrict__ loss_acc) {
    __shared__ float partial[4];
    const int wave = threadIdx.x >> 6;
    const int lane = threadIdx.x & 63;
    const int row = blockIdx.x * 4 + wave;

    unsigned long long m = ~0ull;
    if (lane < NPART) m = partials[(size_t)lane * N_VEC + row];
    #pragma unroll
    for (int off = 1; off < NPART; off <<= 1) {
        unsigned long long v = __shfl_xor(m, off);
        if (v < m) m = v;
    }
    m = __shfl(m, 0);
    const int ix = (int)(unsigned)(m & 0xFFFFFFFFull);

    float4 q = *(const float4*)(emb + (size_t)ix * DIM + lane * 4);
    float4 xv = *(const float4*)(x + (size_t)row * DIM + lane * 4);
    *(float4*)(out_q + (size_t)row * DIM + lane * 4) = q;
    float dx = q.x - xv.x, dy = q.y - xv.y, dz = q.z - xv.z, dw = q.w - xv.w;
    float s = dx * dx + dy * dy + dz * dz + dw * dw;
    #pragma unroll
    for (int off = 32; off; off >>= 1) s += __shfl_xor(s, off);
    if (lane == 0) {
        out_ind[row] = (float)ix;
        atomicAdd(&counts[ix], 1u);
        partial[wave] = s;
    }
    __syncthreads();
    if (threadIdx.x == 0)
        atomicAdd(loss_acc, partial[0] + partial[1] + partial[2] + partial[3]);
}

// -------------------------------------------------- entropy / loss finalize
__global__ __launch_bounds__(256) void finalize_kernel(
    const unsigned* __restrict__ counts, const float* __restrict__ loss_acc,
    float* __restrict__ out_scalars) {
    __shared__ float red[256];
    float h = 0.0f;
    for (int c = threadIdx.x; c < M_CODES; c += 256) {
        float p = (float)counts[c] * (1.0f / (float)N_VEC);
        h += p * logf(p + 1e-10f);
    }
    red[threadIdx.x] = h;
    __syncthreads();
    for (int s = 128; s; s >>= 1) {
        if (threadIdx.x < s) red[threadIdx.x] += red[threadIdx.x + s];
        __syncthreads();
    }
    if (threadIdx.x == 0) {
        out_scalars[0] = BETA * loss_acc[0] / (float)(N_VEC * DIM);
        out_scalars[1] = expf(-red[0]);
    }
}

extern "C" void kernel_launch(void* const* d_in, const int* in_sizes, int n_in,
                              void* d_out, int out_size, void* d_ws, size_t ws_size,
                              hipStream_t stream) {
    const float* x = (const float*)d_in[0];
    const float* emb = (const float*)d_in[1];

    float* out = (float*)d_out;
    float* out_q = out;                                   // N*DIM
    float* out_ind = out + (size_t)N_VEC * DIM;           // N
    float* out_scalars = out_ind + N_VEC;                 // 2

    // x hi/lo scratch lives in d_out's quantized region (rewritten by finish)
    ushort* xh = (ushort*)out;                            // 8 MB
    ushort* xl = xh + (size_t)N_VEC * DIM;                // 8 MB

    char* wp = (char*)d_ws;
    ushort* eh = (ushort*)wp;  wp += (size_t)M_CODES * DIM * 2;   // 4 MB
    ushort* el = (ushort*)wp;  wp += (size_t)M_CODES * DIM * 2;   // 4 MB
    float* e2 = (float*)wp;    wp += (size_t)M_CODES * 4;         // 32 KB
    unsigned long long* partials = (unsigned long long*)wp;
    wp += (size_t)NPART * N_VEC * 8;                              // 1 MB
    unsigned* counts = (unsigned*)wp; wp += (size_t)M_CODES * 4;  // 32 KB
    float* loss_acc = (float*)wp;                                 // 4 B

    prep_kernel<<<(N_VEC + M_CODES) / 4, 256, 0, stream>>>(x, emb, xh, xl, eh, el,
                                                           e2, counts, loss_acc);

    hipFuncSetAttribute((const void*)vq_mfma_kernel,
                        hipFuncAttributeMaxDynamicSharedMemorySize, LDS_TOTAL);
    vq_mfma_kernel<<<(N_VEC / BM) * NSLICE, 512, LDS_TOTAL, stream>>>(
        xh, xl, eh, el, e2, partials);

    finish_kernel<<<N_VEC / 4, 256, 0, stream>>>(x, emb, partials, out_ind, out_q,
                                                 counts, loss_acc);
    finalize_kernel<<<1, 256, 0, stream>>>(counts, loss_acc, out_scalars);
}

// Round 15
// 262.940 us; speedup vs baseline: 1.1510x; 1.1510x over previous
//
#include <hip/hip_runtime.h>
#include <stdint.h>

// VectorQuantize on MI355X (gfx950) — bf16x3 MFMA distance-GEMM + argmin.
// Round 15: TLP attack — BM=128 x BN=128 blocks (8 waves, wave tile 32x64,
// acc[2][4]), 64KB LDS -> 2 independent blocks/CU = 4 waves/SIMD so one
// block's LDS-read stalls hide under the other's MFMA bursts (m114).
// X2/E2 double buffer, stage(s+1) at step top (full-step latency budget),
// rt-major XCD mapping. d_out: quantized, ind, loss, perplexity.

#define N_VEC 16384
#define M_CODES 8192
#define DIM 256
#define BETA 0.25f

#define NSLICE 4
#define SLICE_CODES 2048
#define BM 128
#define BN 128
#define NPART 8                  // NSLICE * 2 col groups

#define BUFBYTES 32768           // Xh 8K | Xl 8K | Eh 8K | El 8K
#define LDS_TOTAL (2 * BUFBYTES) // 64 KiB -> 2 blocks/CU
#define NSTEPS 128               // 16 ct x 8 kc

typedef __attribute__((ext_vector_type(4))) float f32x4;
typedef __attribute__((ext_vector_type(8))) __bf16 bf16x8;

__device__ __forceinline__ void gll16(const void* g, const void* lds_p) {
    __builtin_amdgcn_global_load_lds(
        (const __attribute__((address_space(1))) uint32_t*)(uintptr_t)g,
        (__attribute__((address_space(3))) uint32_t*)(uint32_t)(uintptr_t)lds_p,
        16, 0, 0);
}
#define SB0() __builtin_amdgcn_sched_barrier(0)

__device__ __forceinline__ ushort f2bf(float f) {
    uint32_t u = __float_as_uint(f);
    return (ushort)((u + 0x7FFFu + ((u >> 16) & 1u)) >> 16);  // RNE
}
__device__ __forceinline__ float bf2f(ushort h) {
    return __uint_as_float(((uint32_t)h) << 16);
}

// ---- fused: split fp32 -> bf16 hi/lo for x and e, e2, zero counts/loss ----
__global__ __launch_bounds__(256) void prep_kernel(
    const float* __restrict__ x, const float* __restrict__ emb,
    ushort* __restrict__ xh, ushort* __restrict__ xl,
    ushort* __restrict__ eh, ushort* __restrict__ el,
    float* __restrict__ e2, unsigned* __restrict__ counts,
    float* __restrict__ loss_acc) {
    if (blockIdx.x < 8) {
        int4 z = {0, 0, 0, 0};
        ((int4*)counts)[blockIdx.x * 256 + threadIdx.x] = z;
        if (blockIdx.x == 0 && threadIdx.x == 0) *loss_acc = 0.0f;
    }
    const int wave = threadIdx.x >> 6;
    const int lane = threadIdx.x & 63;
    const int row = blockIdx.x * 4 + wave;

    const float* src;
    ushort* ph;
    ushort* pl;
    bool is_e;
    int er = row - N_VEC;
    if (row < N_VEC) {
        src = x + (size_t)row * DIM;
        ph = xh + (size_t)row * DIM;
        pl = xl + (size_t)row * DIM;
        is_e = false;
    } else {
        src = emb + (size_t)er * DIM;
        ph = eh + (size_t)er * DIM;
        pl = el + (size_t)er * DIM;
        is_e = true;
    }
    float4 v = *(const float4*)(src + lane * 4);
    ushort h0 = f2bf(v.x), h1 = f2bf(v.y), h2 = f2bf(v.z), h3 = f2bf(v.w);
    ushort l0 = f2bf(v.x - bf2f(h0)), l1 = f2bf(v.y - bf2f(h1));
    ushort l2 = f2bf(v.z - bf2f(h2)), l3 = f2bf(v.w - bf2f(h3));
    *(ushort4*)(ph + lane * 4) = make_ushort4(h0, h1, h2, h3);
    *(ushort4*)(pl + lane * 4) = make_ushort4(l0, l1, l2, l3);
    if (is_e) {
        float s = v.x * v.x + v.y * v.y + v.z * v.z + v.w * v.w;
        #pragma unroll
        for (int off = 32; off; off >>= 1) s += __shfl_xor(s, off);
        if (lane == 0) e2[er] = s;
    }
}

// ------ main: bf16x3 MFMA distance GEMM, 8-wave blocks, 2/CU, argmin ----
__global__ __launch_bounds__(512, 4) void vq_mfma_kernel(
    const ushort* __restrict__ xh, const ushort* __restrict__ xl,
    const ushort* __restrict__ eh, const ushort* __restrict__ el,
    const float* __restrict__ e2g, unsigned long long* __restrict__ partials) {
    extern __shared__ char lds[];

    const int t = threadIdx.x;
    const int lane = t & 63;
    const int wv = t >> 6;          // 0..7
    const int lane15 = lane & 15;
    const int l16 = lane >> 4;      // 0..3

    // rt-major mapping: XCD = bid%8 = rt%8 -> X tile L2-resident per XCD
    const int rt = blockIdx.x & 127;
    const int slice = blockIdx.x >> 7;   // 0..3
    const int row0 = rt * BM;
    const int cslice0 = slice * SLICE_CODES;

    const int wr0 = (wv & 3) * 32;   // wave row group 0..96
    const int wch = wv >> 2;         // wave col half (64 codes)

    // ---- fragment LDS byte bases (swizzle term is f-independent)
    const int swz = ((l16 ^ (lane15 >> 1)) & 3) << 4;
    const int byteA0 = (wr0 + lane15) * 64 + swz;
    const int byteB0 = (wch * 64 + lane15) * 64 + swz;

    // ---- staging: linear LDS dest, inverse-swizzled global source
    // 128 rows x 4 chunks = 512 slots of 16B; thread t covers slot t
    const int rs = t >> 2;
    const int cs = ((t & 3) ^ ((t >> 3) & 3)) << 3;   // ushort offset

    const ushort* pxh = xh + (size_t)(row0 + rs) * DIM + cs;
    const ushort* pxl = xl + (size_t)(row0 + rs) * DIM + cs;
    const ushort* peh = eh + (size_t)(cslice0 + rs) * DIM + cs;
    const ushort* pel = el + (size_t)(cslice0 + rs) * DIM + cs;
    const int wdst = wv * 1024;   // wave-uniform LDS dest offset

    auto stage = [&](int bufOff, int s) {   // 4 gll per thread
        char* b = lds + bufOff + wdst;
        const int xo = (s & 7) * 32;                               // kc*32 elems
        const size_t eo = ((size_t)(s >> 3) << 15) + (s & 7) * 32; // ct*BN*DIM + kc*32
        gll16(pxh + xo, b);
        gll16(pxl + xo, b + 8192);
        gll16(peh + eo, b + 16384);
        gll16(pel + eo, b + 24576);
    };

    float best[8];
    int bidx[8];
    #pragma unroll
    for (int s = 0; s < 8; ++s) { best[s] = __uint_as_float(0x7f800000u); bidx[s] = 0; }

    f32x4 acc[2][4];
    #pragma unroll
    for (int fi = 0; fi < 2; ++fi)
        #pragma unroll
        for (int fj = 0; fj < 4; ++fj) acc[fi][fj] = (f32x4){0.f, 0.f, 0.f, 0.f};

    float e2r[4];

    // prologue: stage step 0 into buffer 0
    stage(0, 0); SB0();

    for (int s = 0; s < NSTEPS; ++s) {
        // entry: stage(s) was issued a full step ago -> near-free drain
        asm volatile("s_waitcnt vmcnt(0)" ::: "memory");
        __builtin_amdgcn_s_barrier();
        SB0();
        if (s + 1 < NSTEPS) { stage(((s + 1) & 1) * BUFBYTES, s + 1); SB0(); }
        if ((s & 7) == 0) {
            const int cb = cslice0 + (s >> 3) * BN + wch * 64 + lane15;
            #pragma unroll
            for (int fj = 0; fj < 4; ++fj) e2r[fj] = e2g[cb + fj * 16];
            SB0();
        }

        const char* lb = lds + (s & 1) * BUFBYTES;
        bf16x8 ah[2], alo[2];
        #pragma unroll
        for (int f = 0; f < 2; ++f) {
            ah[f] = *(const bf16x8*)(lb + byteA0 + f * 1024);
            alo[f] = *(const bf16x8*)(lb + 8192 + byteA0 + f * 1024);
        }
        __builtin_amdgcn_s_setprio(1);
        #pragma unroll
        for (int fj = 0; fj < 4; ++fj) {
            bf16x8 bh = *(const bf16x8*)(lb + 16384 + byteB0 + fj * 1024);
            bf16x8 blo = *(const bf16x8*)(lb + 24576 + byteB0 + fj * 1024);
            #pragma unroll
            for (int fi = 0; fi < 2; ++fi)
                acc[fi][fj] = __builtin_amdgcn_mfma_f32_16x16x32_bf16(
                    ah[fi], bh, acc[fi][fj], 0, 0, 0);
            #pragma unroll
            for (int fi = 0; fi < 2; ++fi)
                acc[fi][fj] = __builtin_amdgcn_mfma_f32_16x16x32_bf16(
                    ah[fi], blo, acc[fi][fj], 0, 0, 0);
            #pragma unroll
            for (int fi = 0; fi < 2; ++fi)
                acc[fi][fj] = __builtin_amdgcn_mfma_f32_16x16x32_bf16(
                    alo[fi], bh, acc[fi][fj], 0, 0, 0);
        }
        __builtin_amdgcn_s_setprio(0);

        if ((s & 7) == 7) {
            // epilogue for ct = s>>3: score = e2[c] - 2*dot
            // C/D layout: col = lane15, row = l16*4 + r
            const int ct = s >> 3;
            const int cb = cslice0 + ct * BN + wch * 64 + lane15;
            #pragma unroll
            for (int fj = 0; fj < 4; ++fj) {
                const int c = cb + fj * 16;
                #pragma unroll
                for (int fi = 0; fi < 2; ++fi)
                    #pragma unroll
                    for (int r = 0; r < 4; ++r) {
                        float sc = e2r[fj] - 2.0f * acc[fi][fj][r];
                        const int slot = fi * 4 + r;
                        if (sc < best[slot]) { best[slot] = sc; bidx[slot] = c; }
                    }
            }
            #pragma unroll
            for (int fi = 0; fi < 2; ++fi)
                #pragma unroll
                for (int fj = 0; fj < 4; ++fj)
                    acc[fi][fj] = (f32x4){0.f, 0.f, 0.f, 0.f};
        }
    }

    // reduce across the 16 lanes sharing each row; ties -> lowest index
    #pragma unroll
    for (int slot = 0; slot < 8; ++slot) {
        float v = best[slot];
        int ix = bidx[slot];
        #pragma unroll
        for (int off = 1; off < 16; off <<= 1) {
            float v2 = __shfl_xor(v, off);
            int ix2 = __shfl_xor(ix, off);
            if (v2 < v || (v2 == v && ix2 < ix)) { v = v2; ix = ix2; }
        }
        if (lane15 == 0) {
            int fi = slot >> 2, r = slot & 3;
            int row = row0 + wr0 + fi * 16 + l16 * 4 + r;
            uint32_t u = __float_as_uint(v);
            uint32_t ord = (u & 0x80000000u) ? ~u : (u | 0x80000000u);
            partials[(size_t)(slice * 2 + wch) * N_VEC + row] =
                ((unsigned long long)ord << 32) | (unsigned)ix;
        }
    }
}

// ---------------- fused: per-row min over partials + gather + loss + counts
__global__ __launch_bounds__(256) void finish_kernel(
    const float* __restrict__ x, const float* __restrict__ emb,
    const unsigned long long* __restrict__ partials,
    float* __restrict__ out_ind, float* __restrict__ out_q,
    unsigned* __restrict__ counts, float* __restrict__ loss_acc) {
    __shared__ float partial[4];
    const int wave = threadIdx.x >> 6;
    const int lane = threadIdx.x & 63;
    const int row = blockIdx.x * 4 + wave;

    unsigned long long m = ~0ull;
    if (lane < NPART) m = partials[(size_t)lane * N_VEC + row];
    #pragma unroll
    for (int off = 1; off < NPART; off <<= 1) {
        unsigned long long v = __shfl_xor(m, off);
        if (v < m) m = v;
    }
    m = __shfl(m, 0);
    const int ix = (int)(unsigned)(m & 0xFFFFFFFFull);

    float4 q = *(const float4*)(emb + (size_t)ix * DIM + lane * 4);
    float4 xv = *(const float4*)(x + (size_t)row * DIM + lane * 4);
    *(float4*)(out_q + (size_t)row * DIM + lane * 4) = q;
    float dx = q.x - xv.x, dy = q.y - xv.y, dz = q.z - xv.z, dw = q.w - xv.w;
    float s = dx * dx + dy * dy + dz * dz + dw * dw;
    #pragma unroll
    for (int off = 32; off; off >>= 1) s += __shfl_xor(s, off);
    if (lane == 0) {
        out_ind[row] = (float)ix;
        atomicAdd(&counts[ix], 1u);
        partial[wave] = s;
    }
    __syncthreads();
    if (threadIdx.x == 0)
        atomicAdd(loss_acc, partial[0] + partial[1] + partial[2] + partial[3]);
}

// -------------------------------------------------- entropy / loss finalize
__global__ __launch_bounds__(256) void finalize_kernel(
    const unsigned* __restrict__ counts, const float* __restrict__ loss_acc,
    float* __restrict__ out_scalars) {
    __shared__ float red[256];
    float h = 0.0f;
    for (int c = threadIdx.x; c < M_CODES; c += 256) {
        float p = (float)counts[c] * (1.0f / (float)N_VEC);
        h += p * logf(p + 1e-10f);
    }
    red[threadIdx.x] = h;
    __syncthreads();
    for (int s = 128; s; s >>= 1) {
        if (threadIdx.x < s) red[threadIdx.x] += red[threadIdx.x + s];
        __syncthreads();
    }
    if (threadIdx.x == 0) {
        out_scalars[0] = BETA * loss_acc[0] / (float)(N_VEC * DIM);
        out_scalars[1] = expf(-red[0]);
    }
}

extern "C" void kernel_launch(void* const* d_in, const int* in_sizes, int n_in,
                              void* d_out, int out_size, void* d_ws, size_t ws_size,
                              hipStream_t stream) {
    const float* x = (const float*)d_in[0];
    const float* emb = (const float*)d_in[1];

    float* out = (float*)d_out;
    float* out_q = out;                                   // N*DIM
    float* out_ind = out + (size_t)N_VEC * DIM;           // N
    float* out_scalars = out_ind + N_VEC;                 // 2

    // x hi/lo scratch lives in d_out's quantized region (rewritten by finish)
    ushort* xh = (ushort*)out;                            // 8 MB
    ushort* xl = xh + (size_t)N_VEC * DIM;                // 8 MB

    char* wp = (char*)d_ws;
    ushort* eh = (ushort*)wp;  wp += (size_t)M_CODES * DIM * 2;   // 4 MB
    ushort* el = (ushort*)wp;  wp += (size_t)M_CODES * DIM * 2;   // 4 MB
    float* e2 = (float*)wp;    wp += (size_t)M_CODES * 4;         // 32 KB
    unsigned long long* partials = (unsigned long long*)wp;
    wp += (size_t)NPART * N_VEC * 8;                              // 1 MB
    unsigned* counts = (unsigned*)wp; wp += (size_t)M_CODES * 4;  // 32 KB
    float* loss_acc = (float*)wp;                                 // 4 B

    prep_kernel<<<(N_VEC + M_CODES) / 4, 256, 0, stream>>>(x, emb, xh, xl, eh, el,
                                                           e2, counts, loss_acc);

    hipFuncSetAttribute((const void*)vq_mfma_kernel,
                        hipFuncAttributeMaxDynamicSharedMemorySize, LDS_TOTAL);
    vq_mfma_kernel<<<(N_VEC / BM) * NSLICE, 512, LDS_TOTAL, stream>>>(
        xh, xl, eh, el, e2, partials);

    finish_kernel<<<N_VEC / 4, 256, 0, stream>>>(x, emb, partials, out_ind, out_q,
                                                 counts, loss_acc);
    finalize_kernel<<<1, 256, 0, stream>>>(counts, loss_acc, out_scalars);
}